// Round 4
// baseline (378.079 us; speedup 1.0000x reference)
//
#include <hip/hip_runtime.h>
#include <stdint.h>

#define M_ROWS 4096   // BATCH*SEQ
#define N_OUT  4096   // OUT_FEATURES
#define K_IN   4096   // IN_FEATURES
#define NNZ_N  1677722

typedef __attribute__((ext_vector_type(8))) short  bf16x8_t;  // 8 bf16 in 4 VGPRs
typedef __attribute__((ext_vector_type(4))) float  f32x4_t;

// ---------- fp32 -> bf16 (RNE) ----------
__device__ __forceinline__ unsigned short f2bf(float f) {
    union { float f; uint32_t u; } v; v.f = f;
    uint32_t u = v.u;
    u += 0x7FFFu + ((u >> 16) & 1u);   // round-to-nearest-even
    return (unsigned short)(u >> 16);
}

// ---------- fused: zero W_f32 accumulator + convert x to bf16 ----------
__global__ void zero_and_convert_x(float4* __restrict__ Wz,
                                   const float4* __restrict__ x,
                                   ushort4* __restrict__ xo) {
    int i = blockIdx.x * blockDim.x + threadIdx.x;  // exact-size grid
    Wz[i] = (float4){0.f, 0.f, 0.f, 0.f};
    float4 v = x[i];
    ushort4 o;
    o.x = f2bf(v.x); o.y = f2bf(v.y); o.z = f2bf(v.z); o.w = f2bf(v.w);
    xo[i] = o;
}

__global__ void convert_f32_bf16(const float4* __restrict__ src,
                                 ushort4* __restrict__ dst) {
    int i = blockIdx.x * blockDim.x + threadIdx.x;
    float4 v = src[i];
    ushort4 o;
    o.x = f2bf(v.x); o.y = f2bf(v.y); o.z = f2bf(v.z); o.w = f2bf(v.w);
    dst[i] = o;
}

// ---------- COO scatter-add, 8 entries/thread for atomic MLP ----------
// R3 analysis: 1-atomic/thread scatter ran ~145us (4x its 34us traffic floor)
// -> latency-bound on ~900cyc random HBM RMW. 8 independent atomics per
// thread + dwordx4 COO loads raise in-flight RMWs 8x.
__global__ void scatter_coo8(const float* __restrict__ data,
                             const int* __restrict__ rows,
                             const int* __restrict__ cols,
                             float* __restrict__ W) {
    const int gtid  = blockIdx.x * blockDim.x + threadIdx.x;
    const int start = gtid * 8;
    if (start + 8 <= NNZ_N) {
        // vector path: two float4/int4 loads per array (aligned: start%4==0)
        const float4 d0 = ((const float4*)data)[start / 4];
        const float4 d1 = ((const float4*)data)[start / 4 + 1];
        const int4   r0 = ((const int4*)rows)[start / 4];
        const int4   r1 = ((const int4*)rows)[start / 4 + 1];
        const int4   c0 = ((const int4*)cols)[start / 4];
        const int4   c1 = ((const int4*)cols)[start / 4 + 1];
        atomicAdd(&W[(size_t)r0.x * K_IN + c0.x], d0.x);
        atomicAdd(&W[(size_t)r0.y * K_IN + c0.y], d0.y);
        atomicAdd(&W[(size_t)r0.z * K_IN + c0.z], d0.z);
        atomicAdd(&W[(size_t)r0.w * K_IN + c0.w], d0.w);
        atomicAdd(&W[(size_t)r1.x * K_IN + c1.x], d1.x);
        atomicAdd(&W[(size_t)r1.y * K_IN + c1.y], d1.y);
        atomicAdd(&W[(size_t)r1.z * K_IN + c1.z], d1.z);
        atomicAdd(&W[(size_t)r1.w * K_IN + c1.w], d1.w);
    } else if (start < NNZ_N) {
        // scalar tail (last partial group of 8)
        for (int i = start; i < NNZ_N; ++i)
            atomicAdd(&W[(size_t)rows[i] * K_IN + cols[i]], data[i]);
    }
}

// ---------- async global->LDS helper (width 16B) ----------
__device__ __forceinline__ void async_ld16(const void* g, void* lds_wave_base) {
    __builtin_amdgcn_global_load_lds(
        (const __attribute__((address_space(1))) uint32_t*)g,
        (__attribute__((address_space(3))) uint32_t*)lds_wave_base,
        16, 0, 0);
}

// ---------- C[M][N] = A[M][K] * B[N][K]^T, bf16 inputs, fp32 out ----------
// 128x128 block tile, BK=32, 256 threads = 4 waves (2x2 of 64x64 wave tiles),
// each wave: 4x4 grid of 16x16x32 MFMAs.
// LDS XOR-swizzled (R2: SQ_LDS_BANK_CONFLICT=0).
// __launch_bounds__(256,4): 4 blocks/CU resident (R3: VGPR 92->60, occ 22->37%,
// gemm 203->170us). Do not raise acc tile without re-checking this budget.
__global__ __launch_bounds__(256, 4) void gemm_bt(const unsigned short* __restrict__ A,
                                                  const unsigned short* __restrict__ B,
                                                  float* __restrict__ C) {
    __shared__ __align__(16) unsigned short sA[128 * 32];
    __shared__ __align__(16) unsigned short sB[128 * 32];

    const int t    = threadIdx.x;
    const int wave = t >> 6;
    const int lane = t & 63;
    const int wr   = wave >> 1;       // wave row (0..1)
    const int wc   = wave & 1;        // wave col (0..1)
    const int m0   = blockIdx.y * 128;
    const int n0   = blockIdx.x * 128;

    // Staging: tile = 128 rows x 32 k-elems bf16 = 512 x 16B chunks
    //   = 2 instrs x 256 threads. LDS chunk lin = it*256 + t holds global
    //   (row = lin>>2, chunk c_src = (lin&3) ^ ((row>>1)&3)).
    const int r0    = t >> 2;                         // rows 0..63   (instr 0)
    const int r1    = 64 + (t >> 2);                  // rows 64..127 (instr 1)
    const int c_src = ((t & 3) ^ ((t >> 3) & 3)) * 8; // swizzled source chunk

    const unsigned short* gA0 = A + (size_t)(m0 + r0) * K_IN + c_src;
    const unsigned short* gA1 = A + (size_t)(m0 + r1) * K_IN + c_src;
    const unsigned short* gB0 = B + (size_t)(n0 + r0) * K_IN + c_src;
    const unsigned short* gB1 = B + (size_t)(n0 + r1) * K_IN + c_src;

    // wave-uniform LDS bases (HW adds lane*16B)
    unsigned short* lA0 = sA + wave * 512;
    unsigned short* lA1 = sA + 2048 + wave * 512;
    unsigned short* lB0 = sB + wave * 512;
    unsigned short* lB1 = sB + 2048 + wave * 512;

    const int lrow = lane & 15;           // m/n index within 16
    // swizzled k-chunk for frag reads: physical chunk = (lane>>4) ^ ((lrow>>1)&3)
    const int kchunk = ((lane >> 4) ^ ((lrow >> 1) & 3)) * 8;

    f32x4_t acc[4][4];
#pragma unroll
    for (int im = 0; im < 4; ++im)
#pragma unroll
        for (int jn = 0; jn < 4; ++jn)
            acc[im][jn] = (f32x4_t){0.f, 0.f, 0.f, 0.f};

    const int sA_base = (wr * 64 + lrow) * 32 + kchunk;
    const int sB_base = (wc * 64 + lrow) * 32 + kchunk;

    for (int k0 = 0; k0 < K_IN; k0 += 32) {
        async_ld16(gA0 + k0, lA0);
        async_ld16(gA1 + k0, lA1);
        async_ld16(gB0 + k0, lB0);
        async_ld16(gB1 + k0, lB1);
        __syncthreads();   // drains vmcnt (global_load_lds) + barrier

        bf16x8_t af[4], bfr[4];
#pragma unroll
        for (int im = 0; im < 4; ++im)
            af[im] = *(const bf16x8_t*)(sA + sA_base + im * 16 * 32);
#pragma unroll
        for (int jn = 0; jn < 4; ++jn)
            bfr[jn] = *(const bf16x8_t*)(sB + sB_base + jn * 16 * 32);

#pragma unroll
        for (int im = 0; im < 4; ++im)
#pragma unroll
            for (int jn = 0; jn < 4; ++jn)
                acc[im][jn] = __builtin_amdgcn_mfma_f32_16x16x32_bf16(
                    af[im], bfr[jn], acc[im][jn], 0, 0, 0);

        __syncthreads();   // protect LDS before next stage
    }

    // Epilogue: C/D layout col = lane&15, row = (lane>>4)*4 + reg
    const int crow0 = m0 + wr * 64 + (lane >> 4) * 4;
    const int ccol0 = n0 + wc * 64 + lrow;
#pragma unroll
    for (int im = 0; im < 4; ++im)
#pragma unroll
        for (int jn = 0; jn < 4; ++jn)
#pragma unroll
            for (int r = 0; r < 4; ++r)
                C[(size_t)(crow0 + im * 16 + r) * N_OUT + ccol0 + jn * 16] =
                    acc[im][jn][r];
}

extern "C" void kernel_launch(void* const* d_in, const int* in_sizes, int n_in,
                              void* d_out, int out_size, void* d_ws, size_t ws_size,
                              hipStream_t stream) {
    const float* x    = (const float*)d_in[0];   // [2,2048,4096] fp32
    const float* data = (const float*)d_in[1];   // [NNZ]
    const int*   rows = (const int*)d_in[2];
    const int*   cols = (const int*)d_in[3];
    float*       out  = (float*)d_out;           // [2,2048,4096] fp32

    // workspace layout
    float*          W_f32  = (float*)d_ws;                                 // 64 MiB
    unsigned short* W_bf16 = (unsigned short*)((char*)d_ws + (64u << 20)); // 32 MiB
    unsigned short* x_bf16 = (unsigned short*)((char*)d_ws + (96u << 20)); // 32 MiB

    const int conv_blocks = (N_OUT * K_IN) / (4 * 256);  // 16384

    // 1. fused: zero W accumulator + convert x -> bf16
    zero_and_convert_x<<<conv_blocks, 256, 0, stream>>>(
        (float4*)W_f32, (const float4*)x, (ushort4*)x_bf16);

    // 2. scatter COO -> dense fp32 (8 entries/thread for atomic MLP)
    const int sc_blocks = (NNZ_N + 8 * 256 - 1) / (8 * 256);  // 820
    scatter_coo8<<<sc_blocks, 256, 0, stream>>>(data, rows, cols, W_f32);

    // 3. convert W -> bf16
    convert_f32_bf16<<<conv_blocks, 256, 0, stream>>>((const float4*)W_f32, (ushort4*)W_bf16);

    // 4. y = x * W^T via bf16 MFMA GEMM
    dim3 grid(N_OUT / 128, M_ROWS / 128);  // 32 x 32
    gemm_bt<<<grid, 256, 0, stream>>>(x_bf16, W_bf16, out);
}